// Round 3
// baseline (144.982 us; speedup 1.0000x reference)
//
#include <hip/hip_runtime.h>

#define THRESH 1.0f
#define DECAY  0.5f

typedef float f32x4 __attribute__((ext_vector_type(4)));

__global__ __launch_bounds__(256) void lif_kernel(const float* __restrict__ X,
                                                  float* __restrict__ S,
                                                  long long n_neurons) {
    long long idx    = (long long)blockIdx.x * blockDim.x + threadIdx.x;
    long long stride = (long long)gridDim.x * blockDim.x;
    for (long long i = idx; i < n_neurons; i += stride) {
        const f32x4* __restrict__ xp = reinterpret_cast<const f32x4*>(X + i * 8);
        // Plain loads: let X allocate in L2/L3 and stay resident across replays.
        f32x4 x0 = xp[0];
        f32x4 x1 = xp[1];
        float xv[8] = {x0[0], x0[1], x0[2], x0[3], x1[0], x1[1], x1[2], x1[3]};
        float sv[8];
        float mem = 0.0f;
#pragma unroll
        for (int t = 0; t < 8; ++t) {
            mem = mem * DECAY + xv[t];
            bool fired = (mem >= THRESH);
            sv[t] = fired ? 1.0f : 0.0f;
            mem   = fired ? 0.0f : mem;   // v_cndmask
        }
        f32x4 s0 = {sv[0], sv[1], sv[2], sv[3]};
        f32x4 s1 = {sv[4], sv[5], sv[6], sv[7]};
        // Non-temporal stores: evict-first / no-allocate so the write stream
        // does not evict X from the Infinity Cache between graph replays.
        f32x4* __restrict__ op = reinterpret_cast<f32x4*>(S + i * 8);
        __builtin_nontemporal_store(s0, &op[0]);
        __builtin_nontemporal_store(s1, &op[1]);
    }
}

extern "C" void kernel_launch(void* const* d_in, const int* in_sizes, int n_in,
                              void* d_out, int out_size, void* d_ws, size_t ws_size,
                              hipStream_t stream) {
    const float* X = (const float*)d_in[0];
    float* S = (float*)d_out;
    long long n_elems   = (long long)in_sizes[0];
    long long n_neurons = n_elems / 8;   // T = 8, last (contiguous) axis

    const int block = 256;
    long long want_blocks = (n_neurons + block - 1) / block;
    int grid = (int)(want_blocks < 2048 ? want_blocks : 2048);

    lif_kernel<<<grid, block, 0, stream>>>(X, S, n_neurons);
}